// Round 5
// baseline (88.192 us; speedup 1.0000x reference)
//
#include <hip/hip_runtime.h>

#define TT 8192
#define DD 64
#define MODS 4
#define NCH 256
#define CH  32    // TT / NCH
#define QPB 8     // queries per gather block

typedef __attribute__((ext_vector_type(8))) short bf16x8;
typedef __attribute__((ext_vector_type(4))) float f32x4;

// round-to-nearest-even fp32 -> bf16 bits
__device__ __forceinline__ unsigned f2bf1(float x) {
    unsigned u = __float_as_uint(x);
    return (u + 0x7FFFu + ((u >> 16) & 1u)) >> 16;
}
__device__ __forceinline__ unsigned packbf(float a, float b) {
    return f2bf1(a) | (f2bf1(b) << 16);
}

// stage one fp32 W layer [d][c] -> LDS bf16 W^T [c][d] (pitch 72 shorts).
__device__ __forceinline__ void stage_w(const float* __restrict__ Wl,
                                        unsigned short* wb, int c, int dp0)
{
    #pragma unroll
    for (int it = 0; it < 8; ++it) {
        int dp = dp0 + 4 * it;                    // 0..31 (pair of d's)
        float w0 = Wl[(2 * dp)     * DD + c];
        float w1 = Wl[(2 * dp + 1) * DD + c];
        *(unsigned*)&wb[c * 72 + 2 * dp] = packbf(w0, w1);
    }
}

// ---------------------------------------------------------------------------
// Kernel 1: fused MLP (bf16 MFMA) + chunk scan + time extraction.
// This round: Crow stored as PACKED BF16 pairs (e0,e1 of one d in a single
// dword): 16 MB -> 8 MB write. Scan thread map is pair-interleaved
// (d=tid2>>1, e=tid2&1) so packing is one intra-wave shfl_xor; kbuf reads
// become 2-way same-address broadcasts (free). Only the <=32-term in-chunk
// partial is bf16-rounded; cross-chunk prefix (PreC) stays fp32.
// ---------------------------------------------------------------------------
__global__ __launch_bounds__(256)
void mlp_scan(const float* __restrict__ X,
              const float* __restrict__ wq_w, const float* __restrict__ wq_b,
              const float* __restrict__ wk_w, const float* __restrict__ wk_b,
              float* __restrict__ Q, float* __restrict__ Ctot,
              unsigned* __restrict__ Crow2, float* __restrict__ times)
{
    __shared__ unsigned short xbuf[4][16][72];   //  9,216 B
    __shared__ union {
        unsigned short w[2][64][72];             // 18,432 B (layers)
        float          k[64][68];                // 17,408 B (scan phase)
    } wk;
    __shared__ float2 vstash[64];                //    512 B

    const int job = blockIdx.y;
    const float *xin, *Wj, *Bias;
    if (job == 0) { xin = X; Wj = wq_w; Bias = wq_b; }
    else {
        const int m = job - 1;
        xin  = X    + (size_t)m * TT * DD;
        Wj   = wk_w + (size_t)m * 3 * DD * DD;
        Bias = wk_b + (size_t)m * 3 * DD;
    }

    const int t    = threadIdx.x;
    const int wv   = t >> 6;
    const int lane = t & 63;
    const int quad = lane >> 4;
    const int l15  = lane & 15;
    const int row0 = blockIdx.x * 64 + wv * 16;   // this wave's 16 global rows
    unsigned short* xb = &xbuf[wv][0][0];
    const int wc = t & 63, wdp0 = t >> 6;

    // ---- stage this wave's 16x64 fp32 rows as bf16; stash fp32 V/time ----
    {
        const float4* src = (const float4*)(xin + (size_t)row0 * DD);
        #pragma unroll
        for (int k = 0; k < 4; ++k) {
            int f = lane + 64 * k;                // float4 idx 0..255
            int r = f >> 4, c4 = (f & 15) << 2;   // local-wave row, col
            float4 v = src[f];
            if (job > 0) {
                if ((f & 15) == 0)  vstash[wv * 16 + r] = make_float2(v.x, v.y);
                if ((f & 15) == 15) times[(size_t)(job - 1) * TT + row0 + r] = v.w;
            }
            uint2 p = make_uint2(packbf(v.x, v.y), packbf(v.z, v.w));
            *(uint2*)&xb[r * 72 + c4] = p;
        }
    }

    stage_w(Wj, &wk.w[0][0][0], wc, wdp0);

    #pragma unroll
    for (int l = 0; l < 3; ++l) {
        __syncthreads();
        const unsigned short* wb = &wk.w[l & 1][0][0];
        if (l < 2)
            stage_w(Wj + (size_t)(l + 1) * DD * DD, &wk.w[(l + 1) & 1][0][0], wc, wdp0);

        const float* Bl = Bias + l * DD;
        f32x4 acc[4];
        #pragma unroll
        for (int mt = 0; mt < 4; ++mt) {
            float4 b4 = *(const float4*)(Bl + 16 * mt + quad * 4);
            acc[mt][0] = b4.x; acc[mt][1] = b4.y; acc[mt][2] = b4.z; acc[mt][3] = b4.w;
        }

        bf16x8 xf[2];
        #pragma unroll
        for (int kt = 0; kt < 2; ++kt)
            xf[kt] = *(const bf16x8*)&xb[l15 * 72 + quad * 8 + kt * 32];

        #pragma unroll
        for (int mt = 0; mt < 4; ++mt) {
            #pragma unroll
            for (int kt = 0; kt < 2; ++kt) {
                bf16x8 wf = *(const bf16x8*)&wb[(16 * mt + l15) * 72 + quad * 8 + kt * 32];
                acc[mt] = __builtin_amdgcn_mfma_f32_16x16x32_bf16(wf, xf[kt], acc[mt], 0, 0, 0);
            }
        }

        if (l < 2) {
            #pragma unroll
            for (int mt = 0; mt < 4; ++mt) {
                float r0 = fmaxf(acc[mt][0], 0.f), r1 = fmaxf(acc[mt][1], 0.f);
                float r2 = fmaxf(acc[mt][2], 0.f), r3 = fmaxf(acc[mt][3], 0.f);
                uint2 p = make_uint2(packbf(r0, r1), packbf(r2, r3));
                *(uint2*)&xb[l15 * 72 + 16 * mt + quad * 4] = p;
            }
        } else {
            // all waves must finish their wbuf fragment reads before kbuf
            // (which overlays wbuf) is written.
            __syncthreads();
            #pragma unroll
            for (int mt = 0; mt < 4; ++mt) {
                float4 v = make_float4(acc[mt][0], acc[mt][1], acc[mt][2], acc[mt][3]);
                if (job == 0)
                    *(float4*)(Q + (size_t)(row0 + l15) * DD + 16 * mt + quad * 4) = v;
                else
                    *(float4*)(&wk.k[wv * 16 + l15][16 * mt + quad * 4]) = v;
            }
        }
    }

    // ---- fused chunk scan (jobs 1..4): 2 chunks of 32 rows per block ----
    // Pair-interleaved map: d = tid2>>1 (0..63), e = tid2&1. Lane pairs
    // (2k,2k+1) hold e0/e1 of the same d; even lane packs both into one
    // dword via shfl_xor and stores bf16 Crow2. Ctot column order follows
    // the same (d<<1)|e convention (prefix kernel is order-agnostic).
    if (job > 0) {
        __syncthreads();                          // kbuf/vstash complete
        const int m    = job - 1;
        const int chl  = t >> 7;                  // 0..1: local chunk
        const int tid2 = t & 127;
        const int d = tid2 >> 1, e = tid2 & 1;
        const int ch = blockIdx.x * 2 + chl;      // global chunk 0..255
        const size_t rbase2 = ((size_t)m * TT + (size_t)ch * CH) * 64 + d;
        float acc = 0.f;
        #pragma unroll
        for (int j = 0; j < 4; ++j) {
            #pragma unroll
            for (int s = 0; s < 8; ++s) {
                const int r  = j * 8 + s;         // row within chunk 0..31
                const int rr = chl * 32 + r;
                float kv = wk.k[rr][d];           // 2-way same-addr broadcast
                float vv = e ? vstash[rr].y : vstash[rr].x;
                acc = fmaf(kv, vv, acc);
                float part = __shfl_xor(acc, 1, 64);  // partner's acc
                if (!e)
                    Crow2[rbase2 + (size_t)r * 64] = packbf(acc, part);
            }
        }
        Ctot[((size_t)m * NCH + ch) * 128 + tid2] = acc;
    }
}

// ---------------------------------------------------------------------------
// Kernel 2: exclusive chunk prefix, 32 blocks (unchanged; column-order
// agnostic — works on the new (d<<1)|e column convention).
// ---------------------------------------------------------------------------
__global__ __launch_bounds__(256)
void prefix_kernel(const float* __restrict__ Ctot, float* __restrict__ PreC)
{
    __shared__ float hs[16][16];
    const int m   = blockIdx.x >> 3;              // 0..3
    const int cg  = blockIdx.x & 7;               // col group 0..7
    const int sub = threadIdx.x >> 4;             // 0..15: chunk group
    const int cl  = threadIdx.x & 15;             // 0..15
    const int col = cg * 16 + cl;                 // 0..127
    const size_t base = ((size_t)m * NCH + (size_t)sub * 16) * 128 + col;

    float v[16];
    #pragma unroll
    for (int c = 0; c < 16; ++c)
        v[c] = Ctot[base + (size_t)c * 128];      // 16 independent loads
    float tot = 0.f;
    #pragma unroll
    for (int c = 0; c < 16; ++c) tot += v[c];
    hs[sub][cl] = tot;
    __syncthreads();

    float run = 0.f;
    #pragma unroll
    for (int s = 0; s < 15; ++s)
        if (s < sub) run += hs[s][cl];
    #pragma unroll
    for (int c = 0; c < 16; ++c) {
        PreC[base + (size_t)c * 128] = run;       // exclusive prefix
        run += v[c];
    }
}

// ---------------------------------------------------------------------------
// Kernel 3: gather. Crow read is now ONE dword per lane (packed bf16 pair,
// 256 B/row); PreC read is one coalesced float2 per lane (fp32 accuracy for
// the cross-chunk prefix). Inlined binary search unchanged.
// ---------------------------------------------------------------------------
__global__ __launch_bounds__(256)
void gather_kernel(const float* __restrict__ Q,
                   const unsigned* __restrict__ Crow2,
                   const float* __restrict__ PreC,
                   const float* __restrict__ times,
                   float* __restrict__ out)
{
    const int bx   = blockIdx.x;                  // 0..1023
    // XCD-contiguous q ranges: each XCD owns 1024 consecutive queries.
    const int q0   = ((bx & 7) << 10) | ((bx >> 3) << 3);

    __shared__ int   idxs[QPB][MODS];
    __shared__ float red[QPB][MODS][2];

    if (threadIdx.x < QPB * MODS) {
        const int u = threadIdx.x >> 2, mm = threadIdx.x & 3;
        const float t1 = times[q0 + u];           // modality-0 row IS t1
        const float* t2 = times + (size_t)mm * TT;
        int lo = 0, hi = TT;
        #pragma unroll 1
        for (int s = 0; s < 13; ++s) {            // 2^13 == TT
            int mid = (lo + hi) >> 1;
            bool le = (t2[mid] <= t1);
            lo = le ? mid + 1 : lo;
            hi = le ? hi : mid;
        }
        idxs[u][mm] = lo - 1;                     // searchsorted(right) - 1
    }
    __syncthreads();

    const int m    = threadIdx.x >> 6;
    const int lane = threadIdx.x & 63;

    #pragma unroll
    for (int u = 0; u < QPB; ++u) {
        const int q  = q0 + u;
        const int id = idxs[u][m];                // wave-uniform
        float a0 = 0.f, a1 = 0.f;
        if (id >= 0) {
            const float qv = Q[(size_t)q * DD + lane];
            const int cg = id >> 5;               // chunk 0..255
            float2 p2 = *(const float2*)(PreC + ((size_t)(m * NCH + cg) << 7) + 2 * lane);
            unsigned rv = Crow2[((size_t)m * TT + id) * 64 + lane];
            float e0 = __uint_as_float(rv << 16);
            float e1 = __uint_as_float(rv & 0xFFFF0000u);
            a0 = qv * (p2.x + e0);
            a1 = qv * (p2.y + e1);
        }
        #pragma unroll
        for (int off = 32; off > 0; off >>= 1) {
            a0 += __shfl_xor(a0, off, 64);
            a1 += __shfl_xor(a1, off, 64);
        }
        if (lane == 0) { red[u][m][0] = a0; red[u][m][1] = a1; }
    }
    __syncthreads();
    if (threadIdx.x < QPB * 2) {
        const int u = threadIdx.x >> 1, e = threadIdx.x & 1;
        out[((q0 + u) << 1) + e] =
            red[u][0][e] + red[u][1][e] + red[u][2][e] + red[u][3][e];
    }
}

extern "C" void kernel_launch(void* const* d_in, const int* in_sizes, int n_in,
                              void* d_out, int out_size, void* d_ws, size_t ws_size,
                              hipStream_t stream)
{
    const float* X    = (const float*)d_in[0];
    const float* wq_w = (const float*)d_in[1];
    const float* wq_b = (const float*)d_in[2];
    const float* wk_w = (const float*)d_in[3];
    const float* wk_b = (const float*)d_in[4];
    float* out = (float*)d_out;

    float*    ws    = (float*)d_ws;
    float*    Q     = ws;                                   // TT*DD           (2 MB)
    unsigned* Crow2 = (unsigned*)(Q + (size_t)TT * DD);     // MODS*TT*64 u32  (8 MB)
    float*    Ctot  = (float*)(Crow2 + (size_t)MODS * TT * 64); // MODS*NCH*128 (512 KB)
    float*    PreC  = Ctot + (size_t)MODS * NCH * 128;      // MODS*NCH*128    (512 KB)
    float*    times = PreC + (size_t)MODS * NCH * 128;      // MODS*TT         (128 KB)

    mlp_scan     <<<dim3(128, 5), 256, 0, stream>>>(X, wq_w, wq_b, wk_w, wk_b,
                                                    Q, Ctot, Crow2, times);
    prefix_kernel<<<MODS * 8,     256, 0, stream>>>(Ctot, PreC);
    gather_kernel<<<TT / QPB,     256, 0, stream>>>(Q, Crow2, PreC, times, out);
}